// Round 14
// baseline (5540.878 us; speedup 1.0000x reference)
//
#include <hip/hip_runtime.h>
#include <cstdint>
#include <cstddef>

#define NB 256   // batch
#define NT 512   // time steps
#define ND 64    // input dim
#define NH 512   // hidden dim

typedef __attribute__((ext_vector_type(8))) _Float16 half8;
typedef __attribute__((ext_vector_type(4))) float f32x4;
typedef unsigned long long ull;

union H8 { half8 h; ull q[2]; };

__device__ __forceinline__ float tanh_fast(float x) {
  float ax = fabsf(x);
  float e  = __expf(-2.0f * ax);
  float t  = (1.0f - e) * __frcp_rn(1.0f + e);
  return copysignf(t, x);
}

// Pack W (W_hh | W_ih) fp16 fragment-major for the pair layout:
//   unit u = (((kt*2 + hf)*8 + w)*2 + nt)*64 + lane, 8 halves each;
//   n = hf*256 + w*32 + nt*16 + (lane&15); k = kt*32 + (lane>>4)*8 + e;
//   kt<16 -> W_hh[n][k], kt>=16 -> W_ih[n][k-512].
__global__ void prep_kernel(const float* __restrict__ whh,
                            const float* __restrict__ wih,
                            _Float16* __restrict__ wpk) {
  const int id = blockIdx.x * 256 + threadIdx.x;   // 0..36863
  if (id >= 18 * 2 * 8 * 2 * 64) return;
  const int lane = id & 63;
  const int nt   = (id >> 6) & 1;
  const int w    = (id >> 7) & 7;
  const int hf   = (id >> 10) & 1;
  const int kt   = id >> 11;
  const int n    = hf * 256 + w * 32 + nt * 16 + (lane & 15);
  const int kb   = kt * 32 + (lane >> 4) * 8;
  half8 o;
#pragma unroll
  for (int e = 0; e < 8; ++e) {
    const int k = kb + e;
    const float v = (kt < 16) ? whh[(size_t)n * NH + k]
                              : wih[(size_t)n * ND + (k - NH)];
    o[e] = (_Float16)v;
  }
  *(half8*)(wpk + (size_t)id * 8) = o;
}

__global__ void init_kernel(unsigned int* __restrict__ flags) {
  int i = blockIdx.x * 256 + threadIdx.x;
  if (i < 4096) flags[i] = 0u;
}

// out[b][t] = b_ho + partial[0][b][t] + partial[1][b][t]
__global__ void combine_kernel(const float* __restrict__ partial,
                               const float* __restrict__ bho,
                               float* __restrict__ out) {
  int id = blockIdx.x * 256 + threadIdx.x;   // 131072
  out[id] = bho[0] + partial[id] + partial[id + NB * NT];
}

// Pair-split persistent RNN (fp16): 32 blocks = 16 bg x 2 halves, 8 waves.
// Block = 16 batch rows x 256 cols (wave w: 32 cols). W fully in VGPRs
// (144/wave @ 2 waves/SIMD). h fp16 hi+lo split in LDS (full 512 cols).
// Exchange with ONE peer block: per-wave flags, early poll (issued before
// own drain), fetch issued at end of step t and consumed at t+1 after the
// own-half MFMAs (8 of 18 k-tiles need no peer data -> fetch RTT hidden).
// Pair mapped to same XCD: bids {c, c+8}.
__global__ __launch_bounds__(512, 2) void rnn_pair(
    const float* __restrict__ x, const _Float16* __restrict__ wpk,
    const float* __restrict__ bih, const float* __restrict__ bhh,
    const float* __restrict__ who,
    ull* __restrict__ hglob,          // [2 tbuf][16 bg][2 p][16 row][128] ull
    unsigned int* __restrict__ flags, // [(bg*2+hf)*8 + w]*16 u32
    float* __restrict__ partial)      // [2 hf][NB][NT] f32
{
  __shared__ _Float16 hpeer[2][2][16][520];   // 133 KiB [tbuf][plane][row][col]
  __shared__ float posum[2][8][16];

  const int bid  = blockIdx.x;
  const int c8   = bid & 7;
  const int hf   = (bid >> 3) & 1;          // pair {c8, c8+8}: same XCD
  const int b1   = (bid >> 4) & 1;
  const int bg   = c8 * 2 + b1;
  const int w    = threadIdx.x >> 6;        // 0..7
  const int lane = threadIdx.x & 63;
  const int lm   = lane & 15;
  const int lg   = lane >> 4;
  const int lkb  = lg * 8;
  const int bm   = bg * 16;
  const int n0   = hf * 256 + w * 32;
  const int tid  = threadIdx.x;

  // ---- W stationary in VGPRs ----
  half8 wv[18][2];
#pragma unroll
  for (int kt = 0; kt < 18; ++kt)
#pragma unroll
    for (int nt = 0; nt < 2; ++nt)
      wv[kt][nt] = *(const half8*)(wpk +
        (size_t)((((kt * 2 + hf) * 8 + w) * 2 + nt) * 64 + lane) * 8);

  float bv[2], wov[2];
#pragma unroll
  for (int nt = 0; nt < 2; ++nt) {
    const int n = n0 + nt * 16 + lm;
    bv[nt]  = bih[n] + bhh[n];
    wov[nt] = who[n];
  }

  // h(-1) = 0 in hpeer buffer 0
  for (int i = tid; i < 2 * 16 * 520 / 2; i += 512)
    ((unsigned*)&hpeer[0][0][0][0])[i] = 0u;
  __syncthreads();

  const float* xrow = x + (size_t)(bm + lm) * NT * ND + lkb;
  f32x4 xr[4];
#pragma unroll
  for (int xt = 0; xt < 2; ++xt) {
    xr[2 * xt]     = *(const f32x4*)(xrow + xt * 32);
    xr[2 * xt + 1] = *(const f32x4*)(xrow + xt * 32 + 4);
  }

  // fetch decode: peer 256 cols = 2048 ull / 512 thr = 4 consecutive ull
  const int L    = tid * 4;
  const int fp_  = L >> 10;                 // plane
  const int frow = (L >> 6) & 15;
  const int fcu  = L & 63;                  // ull col within peer half
  const int gq0  = (fp_ * 16 + frow) * 128 + (1 - hf) * 64 + fcu;
  const int sboff = ((fp_ * 16 + frow) * 520 + (1 - hf) * 256 + fcu * 4) * 2;

  unsigned int* myflag = flags + ((bg * 2 + hf) * 8 + w) * 16;
  const unsigned int* peerflag = flags + ((bg * 2 + (1 - hf)) * 8 + (lane & 7)) * 16;

  ull fq[4];
  unsigned pv = 0xFFFFFFFFu;

#define XCONV() do {                                                          \
    _Pragma("unroll")                                                         \
    for (int _xt = 0; _xt < 2; ++_xt) {                                       \
      float _v[8];                                                            \
      *(f32x4*)&_v[0] = xr[2 * _xt]; *(f32x4*)&_v[4] = xr[2 * _xt + 1];       \
      _Pragma("unroll")                                                       \
      for (int _e = 0; _e < 8; ++_e) {                                        \
        _Float16 _hi = (_Float16)_v[_e];                                      \
        axh[_xt][_e] = _hi;                                                   \
        axl[_xt][_e] = (_Float16)(_v[_e] - (float)_hi);                       \
      }                                                                       \
    }                                                                         \
  } while (0)

#define XPREF(T1) do {                                                        \
    if ((T1) < NT) {                                                          \
      _Pragma("unroll")                                                       \
      for (int _xt = 0; _xt < 2; ++_xt) {                                     \
        xr[2 * _xt]     = *(const f32x4*)(xrow + (size_t)(T1) * ND + _xt * 32);     \
        xr[2 * _xt + 1] = *(const f32x4*)(xrow + (size_t)(T1) * ND + _xt * 32 + 4); \
      }                                                                       \
    }                                                                         \
  } while (0)

#define MFMA_H(K0, CUR) do {                                                  \
    _Pragma("unroll")                                                         \
    for (int _k = 0; _k < 8; ++_k) {                                          \
      const int _kt = (K0) + _k;                                              \
      half8 _ah = *(const half8*)&hpeer[CUR][0][lm][_kt * 32 + lkb];          \
      half8 _al = *(const half8*)&hpeer[CUR][1][lm][_kt * 32 + lkb];          \
      _Pragma("unroll")                                                       \
      for (int _nt = 0; _nt < 2; ++_nt) {                                     \
        acc[_nt][0] = __builtin_amdgcn_mfma_f32_16x16x32_f16(_ah, wv[_kt][_nt], acc[_nt][0], 0, 0, 0); \
        acc[_nt][1] = __builtin_amdgcn_mfma_f32_16x16x32_f16(_al, wv[_kt][_nt], acc[_nt][1], 0, 0, 0); \
      }                                                                       \
    }                                                                         \
  } while (0)

#define MFMA_X() do {                                                         \
    _Pragma("unroll")                                                         \
    for (int _q = 0; _q < 2; ++_q)                                            \
      _Pragma("unroll")                                                       \
      for (int _nt = 0; _nt < 2; ++_nt) {                                     \
        acc[_nt][0] = __builtin_amdgcn_mfma_f32_16x16x32_f16(axh[_q], wv[16 + _q][_nt], acc[_nt][0], 0, 0, 0); \
        acc[_nt][1] = __builtin_amdgcn_mfma_f32_16x16x32_f16(axl[_q], wv[16 + _q][_nt], acc[_nt][1], 0, 0, 0); \
      }                                                                       \
  } while (0)

#define EPILOGUE(T) do {                                                      \
    float _po[4] = {0.f, 0.f, 0.f, 0.f};                                      \
    _Pragma("unroll")                                                         \
    for (int _nt = 0; _nt < 2; ++_nt) {                                       \
      _Pragma("unroll")                                                       \
      for (int _r = 0; _r < 4; ++_r) {                                        \
        float _pre = acc[_nt][0][_r] + acc[_nt][1][_r] + bv[_nt];             \
        float _hv  = tanh_fast(_pre);                                         \
        const int _m = lg * 4 + _r;                                           \
        _Float16 _hi = (_Float16)_hv;                                         \
        hpeer[((T) + 1) & 1][0][_m][n0 + _nt * 16 + lm] = _hi;                \
        hpeer[((T) + 1) & 1][1][_m][n0 + _nt * 16 + lm] =                     \
            (_Float16)(_hv - (float)_hi);                                     \
        _po[_r] += _hv * wov[_nt];                                            \
      }                                                                       \
    }                                                                         \
    _Pragma("unroll")                                                         \
    for (int _s = 1; _s < 16; _s <<= 1)                                       \
      _Pragma("unroll")                                                       \
      for (int _r = 0; _r < 4; ++_r) _po[_r] += __shfl_xor(_po[_r], _s, 64);  \
    if (lm == 0) {                                                            \
      _Pragma("unroll")                                                       \
      for (int _r = 0; _r < 4; ++_r) posum[(T) & 1][w][lg * 4 + _r] = _po[_r];\
    }                                                                         \
  } while (0)

#define PUBLISH(T) do {                                                       \
    const int _pr = lane >> 2, _pc = (lane & 3) * 8;                          \
    ull* _base = hglob + ((size_t)(((T) + 1) & 1) * 16 + bg) * 4096;          \
    _Pragma("unroll")                                                         \
    for (int _p = 0; _p < 2; ++_p) {                                          \
      H8 _u;                                                                  \
      _u.h = *(const half8*)&hpeer[((T) + 1) & 1][_p][_pr][n0 + _pc];         \
      ull* _d = _base + (_p * 16 + _pr) * 128 + (n0 + _pc) / 4;               \
      __hip_atomic_store(_d,     _u.q[0], __ATOMIC_RELAXED, __HIP_MEMORY_SCOPE_AGENT); \
      __hip_atomic_store(_d + 1, _u.q[1], __ATOMIC_RELAXED, __HIP_MEMORY_SCOPE_AGENT); \
    }                                                                         \
  } while (0)

#define POLLISSUE() do {                                                      \
    pv = 0xFFFFFFFFu;                                                         \
    if (lane < 8)                                                             \
      pv = __hip_atomic_load(peerflag, __ATOMIC_RELAXED, __HIP_MEMORY_SCOPE_AGENT); \
  } while (0)

#define DRAIN() asm volatile("s_waitcnt vmcnt(0)" ::: "memory")

#define FLAGST(T1) do {                                                       \
    if (lane == 0)                                                            \
      __hip_atomic_store(myflag, (unsigned)(T1), __ATOMIC_RELAXED,            \
                         __HIP_MEMORY_SCOPE_AGENT);                           \
  } while (0)

#define SPINREST(T1) do {                                                     \
    while (!__all(pv >= (unsigned)(T1))) {                                    \
      __builtin_amdgcn_s_sleep(1);                                            \
      if (lane < 8)                                                           \
        pv = __hip_atomic_load(peerflag, __ATOMIC_RELAXED, __HIP_MEMORY_SCOPE_AGENT); \
    }                                                                         \
    asm volatile("" ::: "memory");                                            \
  } while (0)

#define FETCH(T) do {                                                         \
    const ull* _gb = hglob + ((size_t)(((T) + 1) & 1) * 16 + bg) * 4096;      \
    _Pragma("unroll")                                                         \
    for (int _j = 0; _j < 4; ++_j)                                            \
      fq[_j] = __hip_atomic_load(_gb + gq0 + _j, __ATOMIC_RELAXED,            \
                                 __HIP_MEMORY_SCOPE_AGENT);                   \
  } while (0)

#define STAGE(CUR) do {                                                       \
    char* _hb = (char*)&hpeer[CUR][0][0][0];                                  \
    _Pragma("unroll")                                                         \
    for (int _j = 0; _j < 4; ++_j) *(ull*)(_hb + sboff + _j * 8) = fq[_j];    \
  } while (0)

  half8 axh[2], axl[2];
  f32x4 acc[2][2];

  // ---------------- prologue t = 0 (h(-1) = 0 in hpeer[0]) ----------------
  XCONV();
  XPREF(1);
  acc[0][0] = (f32x4){0.f,0.f,0.f,0.f}; acc[0][1] = (f32x4){0.f,0.f,0.f,0.f};
  acc[1][0] = (f32x4){0.f,0.f,0.f,0.f}; acc[1][1] = (f32x4){0.f,0.f,0.f,0.f};
  MFMA_H(0, 0); MFMA_H(8, 0);
  MFMA_X();
  EPILOGUE(0);
  PUBLISH(0);
  POLLISSUE();
  DRAIN();
  FLAGST(1);
  SPINREST(1);
  FETCH(0);
  __syncthreads();

  // ---------------- main loop ----------------
  for (int t = 1; t < NT; ++t) {
    const int cur = t & 1;
    XCONV();
    XPREF(t + 1);
    acc[0][0] = (f32x4){0.f,0.f,0.f,0.f}; acc[0][1] = (f32x4){0.f,0.f,0.f,0.f};
    acc[1][0] = (f32x4){0.f,0.f,0.f,0.f}; acc[1][1] = (f32x4){0.f,0.f,0.f,0.f};
    // own half first: no peer data needed; fetch RTT hides under these
    MFMA_H(hf * 8, cur);
    MFMA_X();
    DRAIN();          // fetch fq + x prefetch complete
    STAGE(cur);
    __syncthreads();  // stage visible to all waves; posum(t-1) readable
    if (w == 0 && lane < 16) {
      float s8 = 0.f;
#pragma unroll
      for (int ww = 0; ww < 8; ++ww) s8 += posum[(t - 1) & 1][ww][lane];
      partial[((size_t)hf * NB + bm + lane) * NT + (t - 1)] = s8;
    }
    MFMA_H((1 - hf) * 8, cur);
    EPILOGUE(t);
    PUBLISH(t);
    POLLISSUE();
    DRAIN();
    FLAGST(t + 1);
    SPINREST(t + 1);
    if (t + 1 < NT) FETCH(t);
    __syncthreads();
  }

  // tail: partial[511]
  if (w == 0 && lane < 16) {
    float s8 = 0.f;
#pragma unroll
    for (int ww = 0; ww < 8; ++ww) s8 += posum[(NT - 1) & 1][ww][lane];
    partial[((size_t)hf * NB + bm + lane) * NT + (NT - 1)] = s8;
  }

#undef XCONV
#undef XPREF
#undef MFMA_H
#undef MFMA_X
#undef EPILOGUE
#undef PUBLISH
#undef POLLISSUE
#undef DRAIN
#undef FLAGST
#undef SPINREST
#undef FETCH
#undef STAGE
}

extern "C" void kernel_launch(void* const* d_in, const int* in_sizes, int n_in,
                              void* d_out, int out_size, void* d_ws, size_t ws_size,
                              hipStream_t stream) {
  const float* x   = (const float*)d_in[0];
  const float* wih = (const float*)d_in[1];
  const float* whh = (const float*)d_in[2];
  const float* bih = (const float*)d_in[3];
  const float* bhh = (const float*)d_in[4];
  const float* who = (const float*)d_in[5];
  const float* bho = (const float*)d_in[6];
  float* out = (float*)d_out;

  // ws: wpk 576KB | hglob 1MB | flags 16KB | partial 1MB
  _Float16* wpk = (_Float16*)d_ws;
  ull* hglob = (ull*)(wpk + (size_t)18 * 2 * 8 * 2 * 64 * 8);
  unsigned int* flags = (unsigned int*)(hglob + (size_t)2 * 16 * 4096);
  float* partial = (float*)(flags + 4096);

  init_kernel<<<16, 256, 0, stream>>>(flags);
  prep_kernel<<<144, 256, 0, stream>>>(whh, wih, wpk);
  rnn_pair<<<32, 512, 0, stream>>>(x, wpk, bih, bhh, who, hglob, flags, partial);
  combine_kernel<<<512, 256, 0, stream>>>(partial, bho, out);
}

// Round 15
// 2911.524 us; speedup vs baseline: 1.9031x; 1.9031x over previous
//
#include <hip/hip_runtime.h>
#include <cstdint>
#include <cstddef>

#define NB 256   // batch
#define NT 512   // time steps
#define ND 64    // input dim
#define NH 512   // hidden dim

typedef __attribute__((ext_vector_type(8))) _Float16 half8;
typedef __attribute__((ext_vector_type(4))) float f32x4;
typedef unsigned long long ull;

union H8 { half8 h; ull q[2]; };

__device__ __forceinline__ float tanh_fast(float x) {
  float ax = fabsf(x);
  float e  = __expf(-2.0f * ax);
  float t  = (1.0f - e) * __frcp_rn(1.0f + e);
  return copysignf(t, x);
}

// Pack W (W_hh | W_ih) fp16 fragment-major for the pair layout:
//   unit u = (((kt*2 + hf)*8 + w)*2 + nt)*64 + lane, 8 halves each;
//   n = hf*256 + w*32 + nt*16 + (lane&15); k = kt*32 + (lane>>4)*8 + e;
//   kt<16 -> W_hh[n][k], kt>=16 -> W_ih[n][k-512].
__global__ void prep_kernel(const float* __restrict__ whh,
                            const float* __restrict__ wih,
                            _Float16* __restrict__ wpk) {
  const int id = blockIdx.x * 256 + threadIdx.x;   // 0..36863
  if (id >= 18 * 2 * 8 * 2 * 64) return;
  const int lane = id & 63;
  const int nt   = (id >> 6) & 1;
  const int w    = (id >> 7) & 7;
  const int hf   = (id >> 10) & 1;
  const int kt   = id >> 11;
  const int n    = hf * 256 + w * 32 + nt * 16 + (lane & 15);
  const int kb   = kt * 32 + (lane >> 4) * 8;
  half8 o;
#pragma unroll
  for (int e = 0; e < 8; ++e) {
    const int k = kb + e;
    const float v = (kt < 16) ? whh[(size_t)n * NH + k]
                              : wih[(size_t)n * ND + (k - NH)];
    o[e] = (_Float16)v;
  }
  *(half8*)(wpk + (size_t)id * 8) = o;
}

__global__ void init_kernel(unsigned int* __restrict__ flags) {
  int i = blockIdx.x * 256 + threadIdx.x;
  if (i < 4096) flags[i] = 0u;
}

// out[b][t] = b_ho + partial[0][b][t] + partial[1][b][t]
__global__ void combine_kernel(const float* __restrict__ partial,
                               const float* __restrict__ bho,
                               float* __restrict__ out) {
  int id = blockIdx.x * 256 + threadIdx.x;   // 131072
  out[id] = bho[0] + partial[id] + partial[id + NB * NT];
}

// Pair-split persistent RNN (fp16): 32 blocks = 16 bg x 2 halves, 8 waves.
// Block = 16 batch rows x 256 cols (wave w: 32 cols). W fully in VGPRs.
// R15 fix vs R14: MFMA_H was called with RUNTIME hf*8 -> wv dynamically
// indexed -> scratch (VGPR_Count=92, 5.5ms). Now branch on block-uniform hf
// with LITERAL k-tile bases so every wv access is compile-time (rule #20).
__global__ __launch_bounds__(512, 2) void rnn_pair(
    const float* __restrict__ x, const _Float16* __restrict__ wpk,
    const float* __restrict__ bih, const float* __restrict__ bhh,
    const float* __restrict__ who,
    ull* __restrict__ hglob,          // [2 tbuf][16 bg][2 p][16 row][128] ull
    unsigned int* __restrict__ flags, // [(bg*2+hf)*8 + w]*16 u32
    float* __restrict__ partial)      // [2 hf][NB][NT] f32
{
  __shared__ _Float16 hpeer[2][2][16][520];   // 133 KiB [tbuf][plane][row][col]
  __shared__ float posum[2][8][16];

  const int bid  = blockIdx.x;
  const int c8   = bid & 7;
  const int hf   = (bid >> 3) & 1;          // pair {c8, c8+8}: same XCD
  const int b1   = (bid >> 4) & 1;
  const int bg   = c8 * 2 + b1;
  const int w    = threadIdx.x >> 6;        // 0..7
  const int lane = threadIdx.x & 63;
  const int lm   = lane & 15;
  const int lg   = lane >> 4;
  const int lkb  = lg * 8;
  const int bm   = bg * 16;
  const int n0   = hf * 256 + w * 32;
  const int tid  = threadIdx.x;

  // ---- W stationary in VGPRs (all accesses below are static-indexed) ----
  half8 wv[18][2];
#pragma unroll
  for (int kt = 0; kt < 18; ++kt)
#pragma unroll
    for (int nt = 0; nt < 2; ++nt)
      wv[kt][nt] = *(const half8*)(wpk +
        (size_t)((((kt * 2 + hf) * 8 + w) * 2 + nt) * 64 + lane) * 8);

  float bv[2], wov[2];
#pragma unroll
  for (int nt = 0; nt < 2; ++nt) {
    const int n = n0 + nt * 16 + lm;
    bv[nt]  = bih[n] + bhh[n];
    wov[nt] = who[n];
  }

  // h(-1) = 0 in hpeer buffer 0
  for (int i = tid; i < 2 * 16 * 520 / 2; i += 512)
    ((unsigned*)&hpeer[0][0][0][0])[i] = 0u;
  __syncthreads();

  const float* xrow = x + (size_t)(bm + lm) * NT * ND + lkb;
  f32x4 xr[4];
#pragma unroll
  for (int xt = 0; xt < 2; ++xt) {
    xr[2 * xt]     = *(const f32x4*)(xrow + xt * 32);
    xr[2 * xt + 1] = *(const f32x4*)(xrow + xt * 32 + 4);
  }

  // fetch decode: peer 256 cols = 2048 ull / 512 thr = 4 consecutive ull
  const int L    = tid * 4;
  const int fp_  = L >> 10;                 // plane
  const int frow = (L >> 6) & 15;
  const int fcu  = L & 63;                  // ull col within peer half
  const int gq0  = (fp_ * 16 + frow) * 128 + (1 - hf) * 64 + fcu;
  const int sboff = ((fp_ * 16 + frow) * 520 + (1 - hf) * 256 + fcu * 4) * 2;

  unsigned int* myflag = flags + ((bg * 2 + hf) * 8 + w) * 16;
  const unsigned int* peerflag = flags + ((bg * 2 + (1 - hf)) * 8 + (lane & 7)) * 16;

  ull fq[4];
  unsigned pv = 0xFFFFFFFFu;

#define XCONV() do {                                                          \
    _Pragma("unroll")                                                         \
    for (int _xt = 0; _xt < 2; ++_xt) {                                       \
      float _v[8];                                                            \
      *(f32x4*)&_v[0] = xr[2 * _xt]; *(f32x4*)&_v[4] = xr[2 * _xt + 1];       \
      _Pragma("unroll")                                                       \
      for (int _e = 0; _e < 8; ++_e) {                                        \
        _Float16 _hi = (_Float16)_v[_e];                                      \
        axh[_xt][_e] = _hi;                                                   \
        axl[_xt][_e] = (_Float16)(_v[_e] - (float)_hi);                       \
      }                                                                       \
    }                                                                         \
  } while (0)

#define XPREF(T1) do {                                                        \
    if ((T1) < NT) {                                                          \
      _Pragma("unroll")                                                       \
      for (int _xt = 0; _xt < 2; ++_xt) {                                     \
        xr[2 * _xt]     = *(const f32x4*)(xrow + (size_t)(T1) * ND + _xt * 32);     \
        xr[2 * _xt + 1] = *(const f32x4*)(xrow + (size_t)(T1) * ND + _xt * 32 + 4); \
      }                                                                       \
    }                                                                         \
  } while (0)

// K0 MUST be a literal constant (rule #20): wv stays in registers.
#define MFMA_H(K0, CUR) do {                                                  \
    _Pragma("unroll")                                                         \
    for (int _k = 0; _k < 8; ++_k) {                                          \
      half8 _ah = *(const half8*)&hpeer[CUR][0][lm][((K0) + _k) * 32 + lkb];  \
      half8 _al = *(const half8*)&hpeer[CUR][1][lm][((K0) + _k) * 32 + lkb];  \
      _Pragma("unroll")                                                       \
      for (int _nt = 0; _nt < 2; ++_nt) {                                     \
        acc[_nt][0] = __builtin_amdgcn_mfma_f32_16x16x32_f16(_ah, wv[(K0) + _k][_nt], acc[_nt][0], 0, 0, 0); \
        acc[_nt][1] = __builtin_amdgcn_mfma_f32_16x16x32_f16(_al, wv[(K0) + _k][_nt], acc[_nt][1], 0, 0, 0); \
      }                                                                       \
    }                                                                         \
  } while (0)

#define MFMA_X() do {                                                         \
    _Pragma("unroll")                                                         \
    for (int _q = 0; _q < 2; ++_q)                                            \
      _Pragma("unroll")                                                       \
      for (int _nt = 0; _nt < 2; ++_nt) {                                     \
        acc[_nt][0] = __builtin_amdgcn_mfma_f32_16x16x32_f16(axh[_q], wv[16 + _q][_nt], acc[_nt][0], 0, 0, 0); \
        acc[_nt][1] = __builtin_amdgcn_mfma_f32_16x16x32_f16(axl[_q], wv[16 + _q][_nt], acc[_nt][1], 0, 0, 0); \
      }                                                                       \
  } while (0)

#define EPILOGUE(T) do {                                                      \
    float _po[4] = {0.f, 0.f, 0.f, 0.f};                                      \
    _Pragma("unroll")                                                         \
    for (int _nt = 0; _nt < 2; ++_nt) {                                       \
      _Pragma("unroll")                                                       \
      for (int _r = 0; _r < 4; ++_r) {                                        \
        float _pre = acc[_nt][0][_r] + acc[_nt][1][_r] + bv[_nt];             \
        float _hv  = tanh_fast(_pre);                                         \
        const int _m = lg * 4 + _r;                                           \
        _Float16 _hi = (_Float16)_hv;                                         \
        hpeer[((T) + 1) & 1][0][_m][n0 + _nt * 16 + lm] = _hi;                \
        hpeer[((T) + 1) & 1][1][_m][n0 + _nt * 16 + lm] =                     \
            (_Float16)(_hv - (float)_hi);                                     \
        _po[_r] += _hv * wov[_nt];                                            \
      }                                                                       \
    }                                                                         \
    _Pragma("unroll")                                                         \
    for (int _s = 1; _s < 16; _s <<= 1)                                       \
      _Pragma("unroll")                                                       \
      for (int _r = 0; _r < 4; ++_r) _po[_r] += __shfl_xor(_po[_r], _s, 64);  \
    if (lm == 0) {                                                            \
      _Pragma("unroll")                                                       \
      for (int _r = 0; _r < 4; ++_r) posum[(T) & 1][w][lg * 4 + _r] = _po[_r];\
    }                                                                         \
  } while (0)

#define PUBLISH(T) do {                                                       \
    const int _pr = lane >> 2, _pc = (lane & 3) * 8;                          \
    ull* _base = hglob + ((size_t)(((T) + 1) & 1) * 16 + bg) * 4096;          \
    _Pragma("unroll")                                                         \
    for (int _p = 0; _p < 2; ++_p) {                                          \
      H8 _u;                                                                  \
      _u.h = *(const half8*)&hpeer[((T) + 1) & 1][_p][_pr][n0 + _pc];         \
      ull* _d = _base + (_p * 16 + _pr) * 128 + (n0 + _pc) / 4;               \
      __hip_atomic_store(_d,     _u.q[0], __ATOMIC_RELAXED, __HIP_MEMORY_SCOPE_AGENT); \
      __hip_atomic_store(_d + 1, _u.q[1], __ATOMIC_RELAXED, __HIP_MEMORY_SCOPE_AGENT); \
    }                                                                         \
  } while (0)

#define POLLISSUE() do {                                                      \
    pv = 0xFFFFFFFFu;                                                         \
    if (lane < 8)                                                             \
      pv = __hip_atomic_load(peerflag, __ATOMIC_RELAXED, __HIP_MEMORY_SCOPE_AGENT); \
  } while (0)

#define DRAIN() asm volatile("s_waitcnt vmcnt(0)" ::: "memory")

#define FLAGST(T1) do {                                                       \
    if (lane == 0)                                                            \
      __hip_atomic_store(myflag, (unsigned)(T1), __ATOMIC_RELAXED,            \
                         __HIP_MEMORY_SCOPE_AGENT);                           \
  } while (0)

#define SPINREST(T1) do {                                                     \
    while (!__all(pv >= (unsigned)(T1))) {                                    \
      __builtin_amdgcn_s_sleep(1);                                            \
      if (lane < 8)                                                           \
        pv = __hip_atomic_load(peerflag, __ATOMIC_RELAXED, __HIP_MEMORY_SCOPE_AGENT); \
    }                                                                         \
    asm volatile("" ::: "memory");                                            \
  } while (0)

#define FETCH(T) do {                                                         \
    const ull* _gb = hglob + ((size_t)(((T) + 1) & 1) * 16 + bg) * 4096;      \
    _Pragma("unroll")                                                         \
    for (int _j = 0; _j < 4; ++_j)                                            \
      fq[_j] = __hip_atomic_load(_gb + gq0 + _j, __ATOMIC_RELAXED,            \
                                 __HIP_MEMORY_SCOPE_AGENT);                   \
  } while (0)

#define STAGE(CUR) do {                                                       \
    char* _hb = (char*)&hpeer[CUR][0][0][0];                                  \
    _Pragma("unroll")                                                         \
    for (int _j = 0; _j < 4; ++_j) *(ull*)(_hb + sboff + _j * 8) = fq[_j];    \
  } while (0)

// drain fetch, stage peer half, barrier, store partial(t-1)
#define STEPMID(T) do {                                                       \
    DRAIN();                                                                  \
    STAGE((T) & 1);                                                           \
    __syncthreads();                                                          \
    if (w == 0 && lane < 16) {                                                \
      float _s8 = 0.f;                                                        \
      _Pragma("unroll")                                                       \
      for (int _ww = 0; _ww < 8; ++_ww) _s8 += posum[((T) - 1) & 1][_ww][lane]; \
      partial[((size_t)hf * NB + bm + lane) * NT + ((T) - 1)] = _s8;          \
    }                                                                         \
  } while (0)

#define STEPTAIL(T) do {                                                      \
    EPILOGUE(T);                                                              \
    PUBLISH(T);                                                               \
    POLLISSUE();                                                              \
    DRAIN();                                                                  \
    FLAGST((T) + 1);                                                          \
    SPINREST((T) + 1);                                                        \
    if ((T) + 1 < NT) FETCH(T);                                               \
    __syncthreads();                                                          \
  } while (0)

#define ACCZERO() do {                                                        \
    acc[0][0] = (f32x4){0.f,0.f,0.f,0.f}; acc[0][1] = (f32x4){0.f,0.f,0.f,0.f}; \
    acc[1][0] = (f32x4){0.f,0.f,0.f,0.f}; acc[1][1] = (f32x4){0.f,0.f,0.f,0.f}; \
  } while (0)

  half8 axh[2], axl[2];
  f32x4 acc[2][2];

  // ---------------- prologue t = 0 (h(-1) = 0 in hpeer[0]) ----------------
  XCONV();
  XPREF(1);
  ACCZERO();
  MFMA_H(0, 0); MFMA_H(8, 0);
  MFMA_X();
  STEPTAIL(0);

  // ---------------- main loop (hf block-uniform: literal k-tile bases) ----
  if (hf == 0) {
    for (int t = 1; t < NT; ++t) {
      const int cur = t & 1;
      XCONV();
      XPREF(t + 1);
      ACCZERO();
      MFMA_H(0, cur);      // own half: cols 0..255, no peer data needed
      MFMA_X();
      STEPMID(t);
      MFMA_H(8, cur);      // peer half, staged above
      STEPTAIL(t);
    }
  } else {
    for (int t = 1; t < NT; ++t) {
      const int cur = t & 1;
      XCONV();
      XPREF(t + 1);
      ACCZERO();
      MFMA_H(8, cur);      // own half: cols 256..511
      MFMA_X();
      STEPMID(t);
      MFMA_H(0, cur);      // peer half
      STEPTAIL(t);
    }
  }

  // tail: partial[511]
  if (w == 0 && lane < 16) {
    float s8 = 0.f;
#pragma unroll
    for (int ww = 0; ww < 8; ++ww) s8 += posum[(NT - 1) & 1][ww][lane];
    partial[((size_t)hf * NB + bm + lane) * NT + (NT - 1)] = s8;
  }

#undef XCONV
#undef XPREF
#undef MFMA_H
#undef MFMA_X
#undef EPILOGUE
#undef PUBLISH
#undef POLLISSUE
#undef DRAIN
#undef FLAGST
#undef SPINREST
#undef FETCH
#undef STAGE
#undef STEPMID
#undef STEPTAIL
#undef ACCZERO
}

extern "C" void kernel_launch(void* const* d_in, const int* in_sizes, int n_in,
                              void* d_out, int out_size, void* d_ws, size_t ws_size,
                              hipStream_t stream) {
  const float* x   = (const float*)d_in[0];
  const float* wih = (const float*)d_in[1];
  const float* whh = (const float*)d_in[2];
  const float* bih = (const float*)d_in[3];
  const float* bhh = (const float*)d_in[4];
  const float* who = (const float*)d_in[5];
  const float* bho = (const float*)d_in[6];
  float* out = (float*)d_out;

  // ws: wpk 576KB | hglob 1MB | flags 16KB | partial 1MB
  _Float16* wpk = (_Float16*)d_ws;
  ull* hglob = (ull*)(wpk + (size_t)18 * 2 * 8 * 2 * 64 * 8);
  unsigned int* flags = (unsigned int*)(hglob + (size_t)2 * 16 * 4096);
  float* partial = (float*)(flags + 4096);

  init_kernel<<<16, 256, 0, stream>>>(flags);
  prep_kernel<<<144, 256, 0, stream>>>(whh, wih, wpk);
  rnn_pair<<<32, 512, 0, stream>>>(x, wpk, bih, bhh, who, hglob, flags, partial);
  combine_kernel<<<512, 256, 0, stream>>>(partial, bho, out);
}

// Round 16
// 1997.713 us; speedup vs baseline: 2.7736x; 1.4574x over previous
//
#include <hip/hip_runtime.h>
#include <cstdint>
#include <cstddef>

#define NB 256   // batch
#define NT 512   // time steps
#define ND 64    // input dim
#define NH 512   // hidden dim

#define GRW   171     // granules per wave-stream (3 halves each, covers 512)
#define STRW  172     // ull stride per wave-stream
#define STRCB 688     // 4 * STRW  (per 128-col chunk)
#define STRBG 2752    // 4 * STRCB (per batch group)
#define STRBUF 44032  // 16 * STRBG (per time-parity buffer)
#define NGTOT 88064   // 2 * STRBUF

typedef __attribute__((ext_vector_type(8))) _Float16 half8;
typedef __attribute__((ext_vector_type(4))) float f32x4;
typedef unsigned long long ull;

__device__ __forceinline__ float tanh_fast(float x) {
  float ax = fabsf(x);
  float e  = __expf(-2.0f * ax);
  float t  = (1.0f - e) * __frcp_rn(1.0f + e);
  return copysignf(t, x);
}
__device__ __forceinline__ unsigned short f16b(float v) {
  _Float16 h = (_Float16)v;
  union { _Float16 h; unsigned short u; } c; c.h = h;
  return c.u;
}

// Pack W (W_hh | W_ih) fp16 fragment-major (same layout as R10, proven):
//   unit u = ((kt*4 + cb)*8 + j)*64 + lane, 8 halves each;
//   n = cb*128 + j*16 + (lane&15); k = kt*32 + (lane>>4)*8 + e;
//   kt<16 -> W_hh[n][k], kt>=16 -> W_ih[n][k-512].
__global__ void prep_kernel(const float* __restrict__ whh,
                            const float* __restrict__ wih,
                            _Float16* __restrict__ wpk) {
  const int id = blockIdx.x * 256 + threadIdx.x;   // 0..36863
  if (id >= 18 * 4 * 8 * 64) return;
  const int lane = id & 63;
  const int j    = (id >> 6) & 7;
  const int cbv  = (id >> 9) & 3;
  const int kt   = id >> 11;
  const int n    = cbv * 128 + j * 16 + (lane & 15);
  const int kb   = kt * 32 + (lane >> 4) * 8;
  half8 o;
#pragma unroll
  for (int e = 0; e < 8; ++e) {
    const int k = kb + e;
    const float v = (kt < 16) ? whh[(size_t)n * NH + k]
                              : wih[(size_t)n * ND + (k - NH)];
    o[e] = (_Float16)v;
  }
  *(half8*)(wpk + (size_t)id * 8) = o;
}

// Zero all granules each call (tag 0 != any expected tag >= 1).
__global__ void init_kernel(ull* __restrict__ hg) {
  int i = blockIdx.x * 256 + threadIdx.x;
  if (i < NGTOT) hg[i] = 0ull;
}

// out[b][t] = b_ho + sum_cb partial[cb][b][t]
__global__ void combine_kernel(const float* __restrict__ partial,
                               const float* __restrict__ bho,
                               float* __restrict__ out) {
  int id = blockIdx.x * 256 + threadIdx.x;   // 131072
  out[id] = bho[0] + partial[id] + partial[id + NB * NT]
          + partial[id + 2 * NB * NT] + partial[id + 3 * NB * NT];
}

// Column-split persistent RNN, fp16 single-plane h, tagged-granule exchange:
// 64 blocks (16 bg x 4 cb) x 4 waves; block = 16 rows x 128 cols.
// W fully VGPR-resident (144 regs). h single fp16 plane in LDS.
// Exchange: 8B granule = 3 fp16 + 16-bit step tag, relaxed agent atomics.
// NO flags, NO drains: tag+data atomic in one 8B store. Consumer pre-issues
// loads at end of previous step, batch-retries only stale granules.
__global__ __launch_bounds__(256) void rnn_tag(
    const float* __restrict__ x, const _Float16* __restrict__ wpk,
    const float* __restrict__ bih, const float* __restrict__ bhh,
    const float* __restrict__ who,
    ull* __restrict__ hglob,        // [2][16 bg][4 cb][4 w][STRW] granules
    float* __restrict__ partial)    // [4 cb][NB][NT] f32
{
  __shared__ unsigned short hpeer[16][522];   // h plane, odd dword row stride
  __shared__ unsigned short tstage[4][520];   // per-wave pub stream (col*16+row)
  __shared__ float posum[2][4][16];

  const int tid  = threadIdx.x;
  const int bid  = blockIdx.x;
  const int bg   = bid >> 2;
  const int cb   = bid & 3;
  const int w    = tid >> 6;
  const int lane = tid & 63;
  const int lm   = lane & 15;
  const int lg   = lane >> 4;
  const int lkb  = lg * 8;
  const int bm   = bg * 16;
  const int n0   = cb * 128 + w * 32;

  // ---- W fully in VGPRs: wv[18 kt][2 nt] (static indexing only) ----
  half8 wv[18][2];
#pragma unroll
  for (int kt = 0; kt < 18; ++kt)
#pragma unroll
    for (int nt = 0; nt < 2; ++nt)
      wv[kt][nt] = *(const half8*)(wpk +
        (size_t)(((kt * 4 + cb) * 8 + (w * 2 + nt)) * 64 + lane) * 8);

  float bv[2], wov[2];
#pragma unroll
  for (int nt = 0; nt < 2; ++nt) {
    const int n = n0 + nt * 16 + lm;
    bv[nt]  = bih[n] + bhh[n];
    wov[nt] = who[n];
  }

  // h(-1) = 0
  for (int i = tid; i < 16 * 522 / 2; i += 256)
    ((unsigned*)&hpeer[0][0])[i] = 0u;
  __syncthreads();

  const float* xrow = x + (size_t)(bm + lm) * NT * ND + lkb;
  f32x4 xr[4];
#pragma unroll
  for (int xt = 0; xt < 2; ++xt) {
    xr[2 * xt]     = *(const f32x4*)(xrow + xt * 32);
    xr[2 * xt + 1] = *(const f32x4*)(xrow + xt * 32 + 4);
  }

  // ---- fetch slot tables: 3 peers x 684 granules = 2052 / 256 -> 9 slots ----
  unsigned foff[9]; int bcol[9], gv[9];
  unsigned fvalid = 0;
#pragma unroll
  for (int k = 0; k < 9; ++k) {
    const int idx = tid + k * 256;
    if (idx < 2052) {
      const int pi  = idx / 684;
      const int rem = idx - pi * 684;
      const int wp  = rem / GRW;
      const int g   = rem - wp * GRW;
      const int scb = pi + (pi >= cb);
      foff[k] = (unsigned)(bg * STRBG + scb * STRCB + wp * STRW + g);
      bcol[k] = scb * 128 + wp * 32;
      gv[k]   = g;
      fvalid |= 1u << k;
    } else { foff[k] = 0; bcol[k] = 0; gv[k] = 0; }
  }
  const unsigned mypub = (unsigned)(bg * STRBG + cb * STRCB + w * STRW);

  ull fq[9];
  half8 ax[2];
  f32x4 acc[2];

  for (int t = 0; t < NT; ++t) {
    if (t > 0) {
      // ---- [A] wait for peer granules of h(t-1): tag == t ----
      const unsigned short tagT = (unsigned short)t;
      const size_t bufb = (size_t)((t + 1) & 1) * STRBUF;   // (t-1)&1
      int iter = 0;
      for (;;) {
        asm volatile("s_waitcnt vmcnt(0)" ::: "memory");
        unsigned pend = 0;
#pragma unroll
        for (int k = 0; k < 9; ++k)
          if ((fvalid >> k & 1u) && (unsigned short)(fq[k] >> 48) != tagT)
            pend |= 1u << k;
        if (__all(pend == 0u)) break;
        if (++iter > (1 << 22)) break;   // safety valve: fail, don't hang
        __builtin_amdgcn_s_sleep(1);
#pragma unroll
        for (int k = 0; k < 9; ++k)
          if (pend >> k & 1u)
            fq[k] = __hip_atomic_load(hglob + bufb + foff[k],
                                      __ATOMIC_RELAXED, __HIP_MEMORY_SCOPE_AGENT);
      }
      // ---- [B] unpack: 3 halves per granule -> hpeer ----
#pragma unroll
      for (int k = 0; k < 9; ++k) {
        if (!(fvalid >> k & 1u)) continue;
        const ull v = fq[k];
        const int g3 = 3 * gv[k];
#pragma unroll
        for (int j = 0; j < 3; ++j) {
          const int p = g3 + j;
          if (p < 512)
            hpeer[p & 15][bcol[k] + (p >> 4)] = (unsigned short)(v >> (16 * j));
        }
      }
      __syncthreads();   // [C] stage visible; posum(t-1) complete
      if (w == 0 && lane < 16) {
        float s4 = posum[(t - 1) & 1][0][lane] + posum[(t - 1) & 1][1][lane]
                 + posum[(t - 1) & 1][2][lane] + posum[(t - 1) & 1][3][lane];
        partial[((size_t)cb * NB + bm + lane) * NT + (t - 1)] = s4;
      }
    }

    // ---- [D] x convert (single fp16) + MFMAs ----
#pragma unroll
    for (int xt = 0; xt < 2; ++xt) {
      float v[8];
      *(f32x4*)&v[0] = xr[2 * xt];
      *(f32x4*)&v[4] = xr[2 * xt + 1];
#pragma unroll
      for (int e = 0; e < 8; ++e) ax[xt][e] = (_Float16)v[e];
    }
    acc[0] = (f32x4){0.f, 0.f, 0.f, 0.f};
    acc[1] = (f32x4){0.f, 0.f, 0.f, 0.f};
#pragma unroll
    for (int kt = 0; kt < 16; ++kt) {
      half8 ah = *(const half8*)&hpeer[lm][kt * 32 + lkb];
      acc[0] = __builtin_amdgcn_mfma_f32_16x16x32_f16(ah, wv[kt][0], acc[0], 0, 0, 0);
      acc[1] = __builtin_amdgcn_mfma_f32_16x16x32_f16(ah, wv[kt][1], acc[1], 0, 0, 0);
    }
#pragma unroll
    for (int q = 0; q < 2; ++q) {
      acc[0] = __builtin_amdgcn_mfma_f32_16x16x32_f16(ax[q], wv[16 + q][0], acc[0], 0, 0, 0);
      acc[1] = __builtin_amdgcn_mfma_f32_16x16x32_f16(ax[q], wv[16 + q][1], acc[1], 0, 0, 0);
    }

    // ---- [E] x(t+1) prefetch ----
    if (t + 1 < NT) {
#pragma unroll
      for (int xt = 0; xt < 2; ++xt) {
        xr[2 * xt]     = *(const f32x4*)(xrow + (size_t)(t + 1) * ND + xt * 32);
        xr[2 * xt + 1] = *(const f32x4*)(xrow + (size_t)(t + 1) * ND + xt * 32 + 4);
      }
    }

    __syncthreads();   // [F] all hpeer reads done before in-place overwrite

    // ---- [G] epilogue: tanh -> hpeer (own) + tstage stream + posum ----
    float po[4] = {0.f, 0.f, 0.f, 0.f};
#pragma unroll
    for (int nt = 0; nt < 2; ++nt) {
#pragma unroll
      for (int r = 0; r < 4; ++r) {
        float pre = acc[nt][r] + bv[nt];
        float hv  = tanh_fast(pre);
        const int m = lg * 4 + r;
        const int c = nt * 16 + lm;
        const unsigned short h16 = f16b(hv);
        hpeer[m][n0 + c] = h16;
        tstage[w][c * 16 + m] = h16;   // stream index p = col*16 + row
        po[r] += hv * wov[nt];
      }
    }
#pragma unroll
    for (int s = 1; s < 16; s <<= 1)
#pragma unroll
      for (int r = 0; r < 4; ++r) po[r] += __shfl_xor(po[r], s, 64);
    if (lm == 0) {
#pragma unroll
      for (int r = 0; r < 4; ++r) posum[t & 1][w][lg * 4 + r] = po[r];
    }

    // ---- pack + publish own wave-stream (tag t+1), fire-and-forget ----
    {
      const ull tagbits = (ull)(unsigned short)(t + 1) << 48;
      const size_t pubb = (size_t)(t & 1) * STRBUF + mypub;
#pragma unroll
      for (int k = 0; k < 3; ++k) {
        const int g2 = lane + k * 64;
        if (g2 < GRW) {
          ull pk = tagbits;
          const int g3 = 3 * g2;
#pragma unroll
          for (int j = 0; j < 3; ++j) {
            const int p = g3 + j;
            if (p < 512) pk |= (ull)tstage[w][p] << (16 * j);
          }
          __hip_atomic_store(hglob + pubb + g2, pk,
                             __ATOMIC_RELAXED, __HIP_MEMORY_SCOPE_AGENT);
        }
      }
    }

    // ---- [H] pre-issue next step's fetch (h(t) granules, tag t+1) ----
    if (t + 1 < NT) {
      const size_t bufb = (size_t)(t & 1) * STRBUF;
#pragma unroll
      for (int k = 0; k < 9; ++k)
        if (fvalid >> k & 1u)
          fq[k] = __hip_atomic_load(hglob + bufb + foff[k],
                                    __ATOMIC_RELAXED, __HIP_MEMORY_SCOPE_AGENT);
    }
  }

  // tail: partial[511]
  __syncthreads();
  if (w == 0 && lane < 16) {
    float s4 = posum[(NT - 1) & 1][0][lane] + posum[(NT - 1) & 1][1][lane]
             + posum[(NT - 1) & 1][2][lane] + posum[(NT - 1) & 1][3][lane];
    partial[((size_t)cb * NB + bm + lane) * NT + (NT - 1)] = s4;
  }
}

extern "C" void kernel_launch(void* const* d_in, const int* in_sizes, int n_in,
                              void* d_out, int out_size, void* d_ws, size_t ws_size,
                              hipStream_t stream) {
  const float* x   = (const float*)d_in[0];
  const float* wih = (const float*)d_in[1];
  const float* whh = (const float*)d_in[2];
  const float* bih = (const float*)d_in[3];
  const float* bhh = (const float*)d_in[4];
  const float* who = (const float*)d_in[5];
  const float* bho = (const float*)d_in[6];
  float* out = (float*)d_out;

  // ws: wpk 576KB | hglob 704KB | partial 2MB
  _Float16* wpk = (_Float16*)d_ws;
  ull* hglob = (ull*)(wpk + (size_t)18 * 4 * 8 * 64 * 8);
  float* partial = (float*)(hglob + (size_t)NGTOT);

  init_kernel<<<(NGTOT + 255) / 256, 256, 0, stream>>>(hglob);
  prep_kernel<<<144, 256, 0, stream>>>(whh, wih, wpk);
  rnn_tag<<<64, 256, 0, stream>>>(x, wpk, bih, bhh, who, hglob, partial);
  combine_kernel<<<512, 256, 0, stream>>>(partial, bho, out);
}

// Round 17
// 1403.411 us; speedup vs baseline: 3.9481x; 1.4235x over previous
//
#include <hip/hip_runtime.h>
#include <cstdint>
#include <cstddef>

#define NB 256   // batch
#define NT 512   // time steps
#define ND 64    // input dim
#define NH 512   // hidden dim

// ---- tagged-granule fallback (R16) constants ----
#define GRW   171
#define STRW  172
#define STRCB 688
#define STRBG 2752
#define STRBUF 44032
#define NGTOT 88064

typedef __attribute__((ext_vector_type(8))) _Float16 half8;
typedef __attribute__((ext_vector_type(4))) float f32x4;
typedef unsigned long long ull;

__device__ __forceinline__ float tanh_fast(float x) {
  float ax = fabsf(x);
  float e  = __expf(-2.0f * ax);
  float t  = (1.0f - e) * __frcp_rn(1.0f + e);
  return copysignf(t, x);
}
__device__ __forceinline__ unsigned short f16b(float v) {
  _Float16 h = (_Float16)v;
  union { _Float16 h; unsigned short u; } c; c.h = h;
  return c.u;
}

// Pack W (W_hh | W_ih) fp16 fragment-major (R10/R16 layout, proven):
//   unit u = kt*32 + (n/16 enumeration); halves off = u*512 + lane*8;
//   n = (u%32)*16 + (lane&15) [via cb*128+j*16 == w*64+nt*16 equivalence];
//   k = kt*32 + (lane>>4)*8 + e; kt<16 -> W_hh, kt>=16 -> W_ih.
__global__ void prep_kernel(const float* __restrict__ whh,
                            const float* __restrict__ wih,
                            _Float16* __restrict__ wpk) {
  const int id = blockIdx.x * 256 + threadIdx.x;   // 0..36863
  if (id >= 18 * 4 * 8 * 64) return;
  const int lane = id & 63;
  const int j    = (id >> 6) & 7;
  const int cbv  = (id >> 9) & 3;
  const int kt   = id >> 11;
  const int n    = cbv * 128 + j * 16 + (lane & 15);
  const int kb   = kt * 32 + (lane >> 4) * 8;
  half8 o;
#pragma unroll
  for (int e = 0; e < 8; ++e) {
    const int k = kb + e;
    const float v = (kt < 16) ? whh[(size_t)n * NH + k]
                              : wih[(size_t)n * ND + (k - NH)];
    o[e] = (_Float16)v;
  }
  *(half8*)(wpk + (size_t)id * 8) = o;
}

// ======================= MAIN PATH (zero-exchange) =======================

// xp precompute: xpf frag layout [bg][t][w][lane][16 halves] (nt*4+r fastest).
// xp = x @ W_ih^T + (b_ih + b_hh), fp16. Grid: 16 bg x 32 tc, 512 thr.
__global__ __launch_bounds__(512) void xp_kernel(
    const float* __restrict__ x, const _Float16* __restrict__ wpk,
    const float* __restrict__ bih, const float* __restrict__ bhh,
    _Float16* __restrict__ xpf)
{
  const int bg   = blockIdx.x >> 5;
  const int tc   = blockIdx.x & 31;
  const int w    = threadIdx.x >> 6;
  const int lane = threadIdx.x & 63;
  const int lm   = lane & 15;
  const int lkb  = (lane >> 4) * 8;
  const int bm   = bg * 16;

  half8 wx[2][4];
#pragma unroll
  for (int q = 0; q < 2; ++q)
#pragma unroll
    for (int nt = 0; nt < 4; ++nt) {
      const int u = (16 + q) * 32 + w * 4 + nt;
      wx[q][nt] = *(const half8*)(wpk + (size_t)u * 512 + lane * 8);
    }
  float bv[4];
#pragma unroll
  for (int nt = 0; nt < 4; ++nt) {
    const int n = w * 64 + nt * 16 + lm;
    bv[nt] = bih[n] + bhh[n];
  }

  for (int tt = 0; tt < 16; ++tt) {
    const int t = tc * 16 + tt;
    const float* xp_ = x + ((size_t)(bm + lm) * NT + t) * ND + lkb;
    half8 ax[2];
#pragma unroll
    for (int q = 0; q < 2; ++q) {
      float v[8];
      *(f32x4*)&v[0] = *(const f32x4*)(xp_ + q * 32);
      *(f32x4*)&v[4] = *(const f32x4*)(xp_ + q * 32 + 4);
#pragma unroll
      for (int e = 0; e < 8; ++e) ax[q][e] = (_Float16)v[e];
    }
    f32x4 acc[4];
#pragma unroll
    for (int nt = 0; nt < 4; ++nt)
      acc[nt] = (f32x4){bv[nt], bv[nt], bv[nt], bv[nt]};
#pragma unroll
    for (int q = 0; q < 2; ++q) {
      acc[0] = __builtin_amdgcn_mfma_f32_16x16x32_f16(ax[q], wx[q][0], acc[0], 0, 0, 0);
      acc[1] = __builtin_amdgcn_mfma_f32_16x16x32_f16(ax[q], wx[q][1], acc[1], 0, 0, 0);
      acc[2] = __builtin_amdgcn_mfma_f32_16x16x32_f16(ax[q], wx[q][2], acc[2], 0, 0, 0);
      acc[3] = __builtin_amdgcn_mfma_f32_16x16x32_f16(ax[q], wx[q][3], acc[3], 0, 0, 0);
    }
    half8 o0, o1;
#pragma unroll
    for (int j = 0; j < 8; ++j) {
      o0[j] = (_Float16)acc[j >> 2][j & 3];
      o1[j] = (_Float16)acc[2 + (j >> 2)][j & 3];
    }
    _Float16* dst = xpf + ((((size_t)bg * NT + t) * 8 + w) * 64 + lane) * 16;
    *(half8*)dst = o0;
    *(half8*)(dst + 8) = o1;
  }
}

// Zero-exchange recurrence: 16 blocks (1 bg each) x 8 waves on ONE CU.
// Wave w owns cols w*64..+63 (4 nt). W_hh kt0..11 in VGPR (192), kt12..15
// in LDS (128 KB). h single fp16 plane in LDS. acc init from xpf (bias
// folded). Only sync = 2 __syncthreads/step. Out written directly.
__global__ __launch_bounds__(512, 2) void rnn_local(
    const _Float16* __restrict__ wpk, const _Float16* __restrict__ xpf,
    const float* __restrict__ who, const float* __restrict__ bho,
    float* __restrict__ out)
{
  __shared__ __align__(16) _Float16 wlds[4][8][4][64][8];  // 128 KiB
  __shared__ __align__(16) _Float16 hst[16][520];          // 16.6 KiB
  __shared__ float posum[8][16];

  const int tid  = threadIdx.x;
  const int bg   = blockIdx.x;
  const int w    = tid >> 6;
  const int lane = tid & 63;
  const int lm   = lane & 15;
  const int lg   = lane >> 4;
  const int lkb  = lg * 8;
  const int bm   = bg * 16;

  // ---- W_hh kt 0..11 -> VGPRs (all static indices) ----
  half8 wv[12][4];
#pragma unroll
  for (int kt = 0; kt < 12; ++kt)
#pragma unroll
    for (int nt = 0; nt < 4; ++nt) {
      const int u = kt * 32 + w * 4 + nt;
      wv[kt][nt] = *(const half8*)(wpk + (size_t)u * 512 + lane * 8);
    }
  // ---- W_hh kt 12..15 -> LDS ----
  for (int i = tid; i < 8192; i += 512) {
    const int ln  = i & 63;
    const int nt  = (i >> 6) & 3;
    const int ww  = (i >> 8) & 7;
    const int ktl = i >> 11;
    const int u   = (12 + ktl) * 32 + ww * 4 + nt;
    *(half8*)&wlds[ktl][ww][nt][ln][0] =
        *(const half8*)(wpk + (size_t)u * 512 + ln * 8);
  }
  float wov[4];
#pragma unroll
  for (int nt = 0; nt < 4; ++nt) wov[nt] = who[w * 64 + nt * 16 + lm];
  const float bo = bho[0];

  // h(-1) = 0
  for (int i = tid; i < 16 * 520 / 2; i += 512)
    ((unsigned*)&hst[0][0])[i] = 0u;
  __syncthreads();

  // xp(0) prefetch
  const _Float16* xpb = xpf + (((size_t)bg * NT * 8 + w) * 64 + lane) * 16;
  half8 xq0 = *(const half8*)xpb;
  half8 xq1 = *(const half8*)(xpb + 8);

  for (int t = 0; t < NT; ++t) {
    // ---- acc init from xp fragments (bias included) ----
    f32x4 acc[4];
    acc[0] = (f32x4){(float)xq0[0], (float)xq0[1], (float)xq0[2], (float)xq0[3]};
    acc[1] = (f32x4){(float)xq0[4], (float)xq0[5], (float)xq0[6], (float)xq0[7]};
    acc[2] = (f32x4){(float)xq1[0], (float)xq1[1], (float)xq1[2], (float)xq1[3]};
    acc[3] = (f32x4){(float)xq1[4], (float)xq1[5], (float)xq1[6], (float)xq1[7]};

    // ---- 16 K-tiles: B from VGPR (0..11) then LDS (12..15) ----
#pragma unroll
    for (int kt = 0; kt < 12; ++kt) {
      half8 ah = *(const half8*)&hst[lm][kt * 32 + lkb];
      acc[0] = __builtin_amdgcn_mfma_f32_16x16x32_f16(ah, wv[kt][0], acc[0], 0, 0, 0);
      acc[1] = __builtin_amdgcn_mfma_f32_16x16x32_f16(ah, wv[kt][1], acc[1], 0, 0, 0);
      acc[2] = __builtin_amdgcn_mfma_f32_16x16x32_f16(ah, wv[kt][2], acc[2], 0, 0, 0);
      acc[3] = __builtin_amdgcn_mfma_f32_16x16x32_f16(ah, wv[kt][3], acc[3], 0, 0, 0);
    }
#pragma unroll
    for (int ktl = 0; ktl < 4; ++ktl) {
      half8 ah = *(const half8*)&hst[lm][(12 + ktl) * 32 + lkb];
      half8 b0 = *(const half8*)&wlds[ktl][w][0][lane][0];
      half8 b1 = *(const half8*)&wlds[ktl][w][1][lane][0];
      half8 b2 = *(const half8*)&wlds[ktl][w][2][lane][0];
      half8 b3 = *(const half8*)&wlds[ktl][w][3][lane][0];
      acc[0] = __builtin_amdgcn_mfma_f32_16x16x32_f16(ah, b0, acc[0], 0, 0, 0);
      acc[1] = __builtin_amdgcn_mfma_f32_16x16x32_f16(ah, b1, acc[1], 0, 0, 0);
      acc[2] = __builtin_amdgcn_mfma_f32_16x16x32_f16(ah, b2, acc[2], 0, 0, 0);
      acc[3] = __builtin_amdgcn_mfma_f32_16x16x32_f16(ah, b3, acc[3], 0, 0, 0);
    }

    // xp(t+1) prefetch (consumed at next acc-init; latency spans 2 barriers)
    if (t + 1 < NT) {
      const _Float16* nx = xpb + (size_t)(t + 1) * 8192;
      xq0 = *(const half8*)nx;
      xq1 = *(const half8*)(nx + 8);
    }

    __syncthreads();   // A: all hst reads complete before overwrite

    // ---- epilogue: tanh -> hst + out partials ----
    float po[4] = {0.f, 0.f, 0.f, 0.f};
#pragma unroll
    for (int nt = 0; nt < 4; ++nt) {
#pragma unroll
      for (int r = 0; r < 4; ++r) {
        float hv = tanh_fast(acc[nt][r]);
        hst[lg * 4 + r][w * 64 + nt * 16 + lm] = (_Float16)hv;
        po[r] += hv * wov[nt];
      }
    }
#pragma unroll
    for (int s = 1; s < 16; s <<= 1)
#pragma unroll
      for (int r = 0; r < 4; ++r) po[r] += __shfl_xor(po[r], s, 64);
    if (lm == 0) {
#pragma unroll
      for (int r = 0; r < 4; ++r) posum[w][lg * 4 + r] = po[r];
    }

    __syncthreads();   // B: h(t) + posum visible

    if (w == 0 && lane < 16) {
      float s8 = 0.f;
#pragma unroll
      for (int ww = 0; ww < 8; ++ww) s8 += posum[ww][lane];
      out[(size_t)(bm + lane) * NT + t] = s8 + bo;
    }
  }
}

// ======================= FALLBACK PATH (R16, proven) =======================

__global__ void init_kernel(ull* __restrict__ hg) {
  int i = blockIdx.x * 256 + threadIdx.x;
  if (i < NGTOT) hg[i] = 0ull;
}
__global__ void combine_kernel(const float* __restrict__ partial,
                               const float* __restrict__ bho,
                               float* __restrict__ out) {
  int id = blockIdx.x * 256 + threadIdx.x;
  out[id] = bho[0] + partial[id] + partial[id + NB * NT]
          + partial[id + 2 * NB * NT] + partial[id + 3 * NB * NT];
}

__global__ __launch_bounds__(256) void rnn_tag(
    const float* __restrict__ x, const _Float16* __restrict__ wpk,
    const float* __restrict__ bih, const float* __restrict__ bhh,
    const float* __restrict__ who,
    ull* __restrict__ hglob, float* __restrict__ partial)
{
  __shared__ unsigned short hpeer[16][522];
  __shared__ unsigned short tstage[4][520];
  __shared__ float posum[2][4][16];

  const int tid  = threadIdx.x;
  const int bid  = blockIdx.x;
  const int bg   = bid >> 2;
  const int cb   = bid & 3;
  const int w    = tid >> 6;
  const int lane = tid & 63;
  const int lm   = lane & 15;
  const int lg   = lane >> 4;
  const int lkb  = lg * 8;
  const int bm   = bg * 16;
  const int n0   = cb * 128 + w * 32;

  half8 wv[18][2];
#pragma unroll
  for (int kt = 0; kt < 18; ++kt)
#pragma unroll
    for (int nt = 0; nt < 2; ++nt)
      wv[kt][nt] = *(const half8*)(wpk +
        (size_t)(((kt * 4 + cb) * 8 + (w * 2 + nt)) * 64 + lane) * 8);

  float bv[2], wov[2];
#pragma unroll
  for (int nt = 0; nt < 2; ++nt) {
    const int n = n0 + nt * 16 + lm;
    bv[nt]  = bih[n] + bhh[n];
    wov[nt] = who[n];
  }
  for (int i = tid; i < 16 * 522 / 2; i += 256)
    ((unsigned*)&hpeer[0][0])[i] = 0u;
  __syncthreads();

  const float* xrow = x + (size_t)(bm + lm) * NT * ND + lkb;
  f32x4 xr[4];
#pragma unroll
  for (int xt = 0; xt < 2; ++xt) {
    xr[2 * xt]     = *(const f32x4*)(xrow + xt * 32);
    xr[2 * xt + 1] = *(const f32x4*)(xrow + xt * 32 + 4);
  }

  unsigned foff[9]; int bcol[9], gv[9];
  unsigned fvalid = 0;
#pragma unroll
  for (int k = 0; k < 9; ++k) {
    const int idx = tid + k * 256;
    if (idx < 2052) {
      const int pi  = idx / 684;
      const int rem = idx - pi * 684;
      const int wp  = rem / GRW;
      const int g   = rem - wp * GRW;
      const int scb = pi + (pi >= cb);
      foff[k] = (unsigned)(bg * STRBG + scb * STRCB + wp * STRW + g);
      bcol[k] = scb * 128 + wp * 32;
      gv[k]   = g;
      fvalid |= 1u << k;
    } else { foff[k] = 0; bcol[k] = 0; gv[k] = 0; }
  }
  const unsigned mypub = (unsigned)(bg * STRBG + cb * STRCB + w * STRW);

  ull fq[9];
  half8 ax[2];
  f32x4 acc[2];

  for (int t = 0; t < NT; ++t) {
    if (t > 0) {
      const unsigned short tagT = (unsigned short)t;
      const size_t bufb = (size_t)((t + 1) & 1) * STRBUF;
      int iter = 0;
      for (;;) {
        asm volatile("s_waitcnt vmcnt(0)" ::: "memory");
        unsigned pend = 0;
#pragma unroll
        for (int k = 0; k < 9; ++k)
          if ((fvalid >> k & 1u) && (unsigned short)(fq[k] >> 48) != tagT)
            pend |= 1u << k;
        if (__all(pend == 0u)) break;
        if (++iter > (1 << 22)) break;
        __builtin_amdgcn_s_sleep(1);
#pragma unroll
        for (int k = 0; k < 9; ++k)
          if (pend >> k & 1u)
            fq[k] = __hip_atomic_load(hglob + bufb + foff[k],
                                      __ATOMIC_RELAXED, __HIP_MEMORY_SCOPE_AGENT);
      }
#pragma unroll
      for (int k = 0; k < 9; ++k) {
        if (!(fvalid >> k & 1u)) continue;
        const ull v = fq[k];
        const int g3 = 3 * gv[k];
#pragma unroll
        for (int j = 0; j < 3; ++j) {
          const int p = g3 + j;
          if (p < 512)
            hpeer[p & 15][bcol[k] + (p >> 4)] = (unsigned short)(v >> (16 * j));
        }
      }
      __syncthreads();
      if (w == 0 && lane < 16) {
        float s4 = posum[(t - 1) & 1][0][lane] + posum[(t - 1) & 1][1][lane]
                 + posum[(t - 1) & 1][2][lane] + posum[(t - 1) & 1][3][lane];
        partial[((size_t)cb * NB + bm + lane) * NT + (t - 1)] = s4;
      }
    }

#pragma unroll
    for (int xt = 0; xt < 2; ++xt) {
      float v[8];
      *(f32x4*)&v[0] = xr[2 * xt];
      *(f32x4*)&v[4] = xr[2 * xt + 1];
#pragma unroll
      for (int e = 0; e < 8; ++e) ax[xt][e] = (_Float16)v[e];
    }
    acc[0] = (f32x4){0.f, 0.f, 0.f, 0.f};
    acc[1] = (f32x4){0.f, 0.f, 0.f, 0.f};
#pragma unroll
    for (int kt = 0; kt < 16; ++kt) {
      half8 ah = *(const half8*)&hpeer[lm][kt * 32 + lkb];
      acc[0] = __builtin_amdgcn_mfma_f32_16x16x32_f16(ah, wv[kt][0], acc[0], 0, 0, 0);
      acc[1] = __builtin_amdgcn_mfma_f32_16x16x32_f16(ah, wv[kt][1], acc[1], 0, 0, 0);
    }
#pragma unroll
    for (int q = 0; q < 2; ++q) {
      acc[0] = __builtin_amdgcn_mfma_f32_16x16x32_f16(ax[q], wv[16 + q][0], acc[0], 0, 0, 0);
      acc[1] = __builtin_amdgcn_mfma_f32_16x16x32_f16(ax[q], wv[16 + q][1], acc[1], 0, 0, 0);
    }
    if (t + 1 < NT) {
#pragma unroll
      for (int xt = 0; xt < 2; ++xt) {
        xr[2 * xt]     = *(const f32x4*)(xrow + (size_t)(t + 1) * ND + xt * 32);
        xr[2 * xt + 1] = *(const f32x4*)(xrow + (size_t)(t + 1) * ND + xt * 32 + 4);
      }
    }
    __syncthreads();

    float po[4] = {0.f, 0.f, 0.f, 0.f};
#pragma unroll
    for (int nt = 0; nt < 2; ++nt) {
#pragma unroll
      for (int r = 0; r < 4; ++r) {
        float hv  = tanh_fast(acc[nt][r] + bv[nt]);
        const int m = lg * 4 + r;
        const int c = nt * 16 + lm;
        const unsigned short h16 = f16b(hv);
        hpeer[m][n0 + c] = h16;
        tstage[w][c * 16 + m] = h16;
        po[r] += hv * wov[nt];
      }
    }
#pragma unroll
    for (int s = 1; s < 16; s <<= 1)
#pragma unroll
      for (int r = 0; r < 4; ++r) po[r] += __shfl_xor(po[r], s, 64);
    if (lm == 0) {
#pragma unroll
      for (int r = 0; r < 4; ++r) posum[t & 1][w][lg * 4 + r] = po[r];
    }

    {
      const ull tagbits = (ull)(unsigned short)(t + 1) << 48;
      const size_t pubb = (size_t)(t & 1) * STRBUF + mypub;
#pragma unroll
      for (int k = 0; k < 3; ++k) {
        const int g2 = lane + k * 64;
        if (g2 < GRW) {
          ull pk = tagbits;
          const int g3 = 3 * g2;
#pragma unroll
          for (int j = 0; j < 3; ++j) {
            const int p = g3 + j;
            if (p < 512) pk |= (ull)tstage[w][p] << (16 * j);
          }
          __hip_atomic_store(hglob + pubb + g2, pk,
                             __ATOMIC_RELAXED, __HIP_MEMORY_SCOPE_AGENT);
        }
      }
    }
    if (t + 1 < NT) {
      const size_t bufb = (size_t)(t & 1) * STRBUF;
#pragma unroll
      for (int k = 0; k < 9; ++k)
        if (fvalid >> k & 1u)
          fq[k] = __hip_atomic_load(hglob + bufb + foff[k],
                                    __ATOMIC_RELAXED, __HIP_MEMORY_SCOPE_AGENT);
    }
  }

  __syncthreads();
  if (w == 0 && lane < 16) {
    float s4 = posum[(NT - 1) & 1][0][lane] + posum[(NT - 1) & 1][1][lane]
             + posum[(NT - 1) & 1][2][lane] + posum[(NT - 1) & 1][3][lane];
    partial[((size_t)cb * NB + bm + lane) * NT + (NT - 1)] = s4;
  }
}

// ======================= host =======================

extern "C" void kernel_launch(void* const* d_in, const int* in_sizes, int n_in,
                              void* d_out, int out_size, void* d_ws, size_t ws_size,
                              hipStream_t stream) {
  const float* x   = (const float*)d_in[0];
  const float* wih = (const float*)d_in[1];
  const float* whh = (const float*)d_in[2];
  const float* bih = (const float*)d_in[3];
  const float* bhh = (const float*)d_in[4];
  const float* who = (const float*)d_in[5];
  const float* bho = (const float*)d_in[6];
  float* out = (float*)d_out;

  _Float16* wpk = (_Float16*)d_ws;                 // 576 KB
  const size_t wpk_halves = (size_t)18 * 4 * 8 * 64 * 8;   // 294912
  const size_t xpf_halves = (size_t)16 * NT * 8 * 64 * 16; // 67,108,864 (128 MB)
  const size_t need_main = (wpk_halves + xpf_halves) * 2 + 1024;

  prep_kernel<<<144, 256, 0, stream>>>(whh, wih, wpk);

  if (ws_size >= need_main) {
    // -------- main: zero-exchange per-CU recurrence --------
    _Float16* xpf = wpk + wpk_halves;
    xp_kernel<<<512, 512, 0, stream>>>(x, wpk, bih, bhh, xpf);
    rnn_local<<<16, 512, 0, stream>>>(wpk, xpf, who, bho, out);
  } else {
    // -------- fallback: R16 tagged-granule pipeline (proven) --------
    ull* hglob = (ull*)(wpk + wpk_halves);
    float* partial = (float*)(hglob + (size_t)NGTOT);
    init_kernel<<<(NGTOT + 255) / 256, 256, 0, stream>>>(hglob);
    rnn_tag<<<64, 256, 0, stream>>>(x, wpk, bih, bhh, who, hglob, partial);
    combine_kernel<<<512, 256, 0, stream>>>(partial, bho, out);
  }
}

// Round 18
// 1328.421 us; speedup vs baseline: 4.1710x; 1.0565x over previous
//
#include <hip/hip_runtime.h>
#include <cstdint>
#include <cstddef>

#define NB 256   // batch
#define NT 512   // time steps
#define ND 64    // input dim
#define NH 512   // hidden dim

// ---- tagged-granule fallback (R16) constants ----
#define GRW   171
#define STRW  172
#define STRCB 688
#define STRBG 2752
#define STRBUF 44032
#define NGTOT 88064

typedef __attribute__((ext_vector_type(8))) _Float16 half8;
typedef __attribute__((ext_vector_type(4))) float f32x4;
typedef unsigned long long ull;

__device__ __forceinline__ float tanh_fast(float x) {
  float ax = fabsf(x);
  float e  = __expf(-2.0f * ax);
  float t  = (1.0f - e) * __frcp_rn(1.0f + e);
  return copysignf(t, x);
}
// Cheap tanh: (e^{2z}-1)/(e^{2z}+1), clamp |x|<=15 (e^30 ~ 1e13, no overflow),
// raw v_rcp_f32 (~1 ulp) instead of __frcp_rn's refine chain. ~10 VALU ops.
__device__ __forceinline__ float tanh_cheap(float x) {
  float z = fminf(fmaxf(x, -15.f), 15.f);
  float e = __expf(2.f * z);
  float d = e + 1.f;
  float r;
  asm("v_rcp_f32 %0, %1" : "=v"(r) : "v"(d));
  return (e - 1.f) * r;
}
__device__ __forceinline__ unsigned short f16b(float v) {
  _Float16 h = (_Float16)v;
  union { _Float16 h; unsigned short u; } c; c.h = h;
  return c.u;
}

// Pack W (W_hh | W_ih) fp16 fragment-major (R10/R16 layout, proven).
__global__ void prep_kernel(const float* __restrict__ whh,
                            const float* __restrict__ wih,
                            _Float16* __restrict__ wpk) {
  const int id = blockIdx.x * 256 + threadIdx.x;   // 0..36863
  if (id >= 18 * 4 * 8 * 64) return;
  const int lane = id & 63;
  const int j    = (id >> 6) & 7;
  const int cbv  = (id >> 9) & 3;
  const int kt   = id >> 11;
  const int n    = cbv * 128 + j * 16 + (lane & 15);
  const int kb   = kt * 32 + (lane >> 4) * 8;
  half8 o;
#pragma unroll
  for (int e = 0; e < 8; ++e) {
    const int k = kb + e;
    const float v = (kt < 16) ? whh[(size_t)n * NH + k]
                              : wih[(size_t)n * ND + (k - NH)];
    o[e] = (_Float16)v;
  }
  *(half8*)(wpk + (size_t)id * 8) = o;
}

// ======================= MAIN PATH (zero-exchange) =======================

// xp precompute: xpf frag layout [bg][t][w][lane][16 halves].
__global__ __launch_bounds__(512) void xp_kernel(
    const float* __restrict__ x, const _Float16* __restrict__ wpk,
    const float* __restrict__ bih, const float* __restrict__ bhh,
    _Float16* __restrict__ xpf)
{
  const int bg   = blockIdx.x >> 5;
  const int tc   = blockIdx.x & 31;
  const int w    = threadIdx.x >> 6;
  const int lane = threadIdx.x & 63;
  const int lm   = lane & 15;
  const int lkb  = (lane >> 4) * 8;
  const int bm   = bg * 16;

  half8 wx[2][4];
#pragma unroll
  for (int q = 0; q < 2; ++q)
#pragma unroll
    for (int nt = 0; nt < 4; ++nt) {
      const int u = (16 + q) * 32 + w * 4 + nt;
      wx[q][nt] = *(const half8*)(wpk + (size_t)u * 512 + lane * 8);
    }
  float bv[4];
#pragma unroll
  for (int nt = 0; nt < 4; ++nt) {
    const int n = w * 64 + nt * 16 + lm;
    bv[nt] = bih[n] + bhh[n];
  }

  for (int tt = 0; tt < 16; ++tt) {
    const int t = tc * 16 + tt;
    const float* xp_ = x + ((size_t)(bm + lm) * NT + t) * ND + lkb;
    half8 ax[2];
#pragma unroll
    for (int q = 0; q < 2; ++q) {
      float v[8];
      *(f32x4*)&v[0] = *(const f32x4*)(xp_ + q * 32);
      *(f32x4*)&v[4] = *(const f32x4*)(xp_ + q * 32 + 4);
#pragma unroll
      for (int e = 0; e < 8; ++e) ax[q][e] = (_Float16)v[e];
    }
    f32x4 acc[4];
#pragma unroll
    for (int nt = 0; nt < 4; ++nt)
      acc[nt] = (f32x4){bv[nt], bv[nt], bv[nt], bv[nt]};
#pragma unroll
    for (int q = 0; q < 2; ++q) {
      acc[0] = __builtin_amdgcn_mfma_f32_16x16x32_f16(ax[q], wx[q][0], acc[0], 0, 0, 0);
      acc[1] = __builtin_amdgcn_mfma_f32_16x16x32_f16(ax[q], wx[q][1], acc[1], 0, 0, 0);
      acc[2] = __builtin_amdgcn_mfma_f32_16x16x32_f16(ax[q], wx[q][2], acc[2], 0, 0, 0);
      acc[3] = __builtin_amdgcn_mfma_f32_16x16x32_f16(ax[q], wx[q][3], acc[3], 0, 0, 0);
    }
    half8 o0, o1;
#pragma unroll
    for (int j = 0; j < 8; ++j) {
      o0[j] = (_Float16)acc[j >> 2][j & 3];
      o1[j] = (_Float16)acc[2 + (j >> 2)][j & 3];
    }
    _Float16* dst = xpf + ((((size_t)bg * NT + t) * 8 + w) * 64 + lane) * 16;
    *(half8*)dst = o0;
    *(half8*)(dst + 8) = o1;
  }
}

// Zero-exchange recurrence: 16 blocks (1 bg each) x 8 waves on ONE CU.
// R18 vs R17: (1) tanh_cheap (halves epilogue VALU ops), (2) xp(t+1)
// prefetch issued at START of MFMA phase so its latency is covered before
// barrier A's implicit vmcnt(0) drain (was issued right before the barrier).
__global__ __launch_bounds__(512, 2) void rnn_local(
    const _Float16* __restrict__ wpk, const _Float16* __restrict__ xpf,
    const float* __restrict__ who, const float* __restrict__ bho,
    float* __restrict__ out)
{
  __shared__ __align__(16) _Float16 wlds[4][8][4][64][8];  // 128 KiB
  __shared__ __align__(16) _Float16 hst[16][520];          // 16.6 KiB
  __shared__ float posum[8][16];

  const int tid  = threadIdx.x;
  const int bg   = blockIdx.x;
  const int w    = tid >> 6;
  const int lane = tid & 63;
  const int lm   = lane & 15;
  const int lg   = lane >> 4;
  const int lkb  = lg * 8;
  const int bm   = bg * 16;

  // ---- W_hh kt 0..11 -> VGPRs (static indices only) ----
  half8 wv[12][4];
#pragma unroll
  for (int kt = 0; kt < 12; ++kt)
#pragma unroll
    for (int nt = 0; nt < 4; ++nt) {
      const int u = kt * 32 + w * 4 + nt;
      wv[kt][nt] = *(const half8*)(wpk + (size_t)u * 512 + lane * 8);
    }
  // ---- W_hh kt 12..15 -> LDS ----
  for (int i = tid; i < 8192; i += 512) {
    const int ln  = i & 63;
    const int nt  = (i >> 6) & 3;
    const int ww  = (i >> 8) & 7;
    const int ktl = i >> 11;
    const int u   = (12 + ktl) * 32 + ww * 4 + nt;
    *(half8*)&wlds[ktl][ww][nt][ln][0] =
        *(const half8*)(wpk + (size_t)u * 512 + ln * 8);
  }
  float wov[4];
#pragma unroll
  for (int nt = 0; nt < 4; ++nt) wov[nt] = who[w * 64 + nt * 16 + lm];
  const float bo = bho[0];

  // h(-1) = 0
  for (int i = tid; i < 16 * 520 / 2; i += 512)
    ((unsigned*)&hst[0][0])[i] = 0u;
  __syncthreads();

  // xp(0) prefetch
  const _Float16* xpb = xpf + (((size_t)bg * NT * 8 + w) * 64 + lane) * 16;
  half8 xq0 = *(const half8*)xpb;
  half8 xq1 = *(const half8*)(xpb + 8);

  for (int t = 0; t < NT; ++t) {
    // ---- acc init from xp fragments (bias folded in) ----
    f32x4 acc[4];
    acc[0] = (f32x4){(float)xq0[0], (float)xq0[1], (float)xq0[2], (float)xq0[3]};
    acc[1] = (f32x4){(float)xq0[4], (float)xq0[5], (float)xq0[6], (float)xq0[7]};
    acc[2] = (f32x4){(float)xq1[0], (float)xq1[1], (float)xq1[2], (float)xq1[3]};
    acc[3] = (f32x4){(float)xq1[4], (float)xq1[5], (float)xq1[6], (float)xq1[7]};

    // ---- xp(t+1) prefetch issued NOW: latency hides under MFMA phase ----
    if (t + 1 < NT) {
      const _Float16* nx = xpb + (size_t)(t + 1) * 8192;
      xq0 = *(const half8*)nx;
      xq1 = *(const half8*)(nx + 8);
    }

    // ---- 16 K-tiles: B from VGPR (0..11) then LDS (12..15) ----
#pragma unroll
    for (int kt = 0; kt < 12; ++kt) {
      half8 ah = *(const half8*)&hst[lm][kt * 32 + lkb];
      acc[0] = __builtin_amdgcn_mfma_f32_16x16x32_f16(ah, wv[kt][0], acc[0], 0, 0, 0);
      acc[1] = __builtin_amdgcn_mfma_f32_16x16x32_f16(ah, wv[kt][1], acc[1], 0, 0, 0);
      acc[2] = __builtin_amdgcn_mfma_f32_16x16x32_f16(ah, wv[kt][2], acc[2], 0, 0, 0);
      acc[3] = __builtin_amdgcn_mfma_f32_16x16x32_f16(ah, wv[kt][3], acc[3], 0, 0, 0);
    }
#pragma unroll
    for (int ktl = 0; ktl < 4; ++ktl) {
      half8 ah = *(const half8*)&hst[lm][(12 + ktl) * 32 + lkb];
      half8 b0 = *(const half8*)&wlds[ktl][w][0][lane][0];
      half8 b1 = *(const half8*)&wlds[ktl][w][1][lane][0];
      half8 b2 = *(const half8*)&wlds[ktl][w][2][lane][0];
      half8 b3 = *(const half8*)&wlds[ktl][w][3][lane][0];
      acc[0] = __builtin_amdgcn_mfma_f32_16x16x32_f16(ah, b0, acc[0], 0, 0, 0);
      acc[1] = __builtin_amdgcn_mfma_f32_16x16x32_f16(ah, b1, acc[1], 0, 0, 0);
      acc[2] = __builtin_amdgcn_mfma_f32_16x16x32_f16(ah, b2, acc[2], 0, 0, 0);
      acc[3] = __builtin_amdgcn_mfma_f32_16x16x32_f16(ah, b3, acc[3], 0, 0, 0);
    }

    __syncthreads();   // A: all hst reads complete (xp load long since landed)

    // ---- epilogue: cheap tanh -> hst + out partials ----
    float po[4] = {0.f, 0.f, 0.f, 0.f};
#pragma unroll
    for (int nt = 0; nt < 4; ++nt) {
#pragma unroll
      for (int r = 0; r < 4; ++r) {
        float hv = tanh_cheap(acc[nt][r]);
        hst[lg * 4 + r][w * 64 + nt * 16 + lm] = (_Float16)hv;
        po[r] += hv * wov[nt];
      }
    }
#pragma unroll
    for (int s = 1; s < 16; s <<= 1)
#pragma unroll
      for (int r = 0; r < 4; ++r) po[r] += __shfl_xor(po[r], s, 64);
    if (lm == 0) {
#pragma unroll
      for (int r = 0; r < 4; ++r) posum[w][lg * 4 + r] = po[r];
    }

    __syncthreads();   // B: h(t) + posum visible

    if (w == 0 && lane < 16) {
      float s8 = 0.f;
#pragma unroll
      for (int ww = 0; ww < 8; ++ww) s8 += posum[ww][lane];
      out[(size_t)(bm + lane) * NT + t] = s8 + bo;   // drains at next barrier A
    }
  }
}

// ======================= FALLBACK PATH (R16, proven) =======================

__global__ void init_kernel(ull* __restrict__ hg) {
  int i = blockIdx.x * 256 + threadIdx.x;
  if (i < NGTOT) hg[i] = 0ull;
}
__global__ void combine_kernel(const float* __restrict__ partial,
                               const float* __restrict__ bho,
                               float* __restrict__ out) {
  int id = blockIdx.x * 256 + threadIdx.x;
  out[id] = bho[0] + partial[id] + partial[id + NB * NT]
          + partial[id + 2 * NB * NT] + partial[id + 3 * NB * NT];
}

__global__ __launch_bounds__(256) void rnn_tag(
    const float* __restrict__ x, const _Float16* __restrict__ wpk,
    const float* __restrict__ bih, const float* __restrict__ bhh,
    const float* __restrict__ who,
    ull* __restrict__ hglob, float* __restrict__ partial)
{
  __shared__ unsigned short hpeer[16][522];
  __shared__ unsigned short tstage[4][520];
  __shared__ float posum[2][4][16];

  const int tid  = threadIdx.x;
  const int bid  = blockIdx.x;
  const int bg   = bid >> 2;
  const int cb   = bid & 3;
  const int w    = tid >> 6;
  const int lane = tid & 63;
  const int lm   = lane & 15;
  const int lg   = lane >> 4;
  const int lkb  = lg * 8;
  const int bm   = bg * 16;
  const int n0   = cb * 128 + w * 32;

  half8 wv[18][2];
#pragma unroll
  for (int kt = 0; kt < 18; ++kt)
#pragma unroll
    for (int nt = 0; nt < 2; ++nt)
      wv[kt][nt] = *(const half8*)(wpk +
        (size_t)(((kt * 4 + cb) * 8 + (w * 2 + nt)) * 64 + lane) * 8);

  float bv[2], wov[2];
#pragma unroll
  for (int nt = 0; nt < 2; ++nt) {
    const int n = n0 + nt * 16 + lm;
    bv[nt]  = bih[n] + bhh[n];
    wov[nt] = who[n];
  }
  for (int i = tid; i < 16 * 522 / 2; i += 256)
    ((unsigned*)&hpeer[0][0])[i] = 0u;
  __syncthreads();

  const float* xrow = x + (size_t)(bm + lm) * NT * ND + lkb;
  f32x4 xr[4];
#pragma unroll
  for (int xt = 0; xt < 2; ++xt) {
    xr[2 * xt]     = *(const f32x4*)(xrow + xt * 32);
    xr[2 * xt + 1] = *(const f32x4*)(xrow + xt * 32 + 4);
  }

  unsigned foff[9]; int bcol[9], gv[9];
  unsigned fvalid = 0;
#pragma unroll
  for (int k = 0; k < 9; ++k) {
    const int idx = tid + k * 256;
    if (idx < 2052) {
      const int pi  = idx / 684;
      const int rem = idx - pi * 684;
      const int wp  = rem / GRW;
      const int g   = rem - wp * GRW;
      const int scb = pi + (pi >= cb);
      foff[k] = (unsigned)(bg * STRBG + scb * STRCB + wp * STRW + g);
      bcol[k] = scb * 128 + wp * 32;
      gv[k]   = g;
      fvalid |= 1u << k;
    } else { foff[k] = 0; bcol[k] = 0; gv[k] = 0; }
  }
  const unsigned mypub = (unsigned)(bg * STRBG + cb * STRCB + w * STRW);

  ull fq[9];
  half8 ax[2];
  f32x4 acc[2];

  for (int t = 0; t < NT; ++t) {
    if (t > 0) {
      const unsigned short tagT = (unsigned short)t;
      const size_t bufb = (size_t)((t + 1) & 1) * STRBUF;
      int iter = 0;
      for (;;) {
        asm volatile("s_waitcnt vmcnt(0)" ::: "memory");
        unsigned pend = 0;
#pragma unroll
        for (int k = 0; k < 9; ++k)
          if ((fvalid >> k & 1u) && (unsigned short)(fq[k] >> 48) != tagT)
            pend |= 1u << k;
        if (__all(pend == 0u)) break;
        if (++iter > (1 << 22)) break;
        __builtin_amdgcn_s_sleep(1);
#pragma unroll
        for (int k = 0; k < 9; ++k)
          if (pend >> k & 1u)
            fq[k] = __hip_atomic_load(hglob + bufb + foff[k],
                                      __ATOMIC_RELAXED, __HIP_MEMORY_SCOPE_AGENT);
      }
#pragma unroll
      for (int k = 0; k < 9; ++k) {
        if (!(fvalid >> k & 1u)) continue;
        const ull v = fq[k];
        const int g3 = 3 * gv[k];
#pragma unroll
        for (int j = 0; j < 3; ++j) {
          const int p = g3 + j;
          if (p < 512)
            hpeer[p & 15][bcol[k] + (p >> 4)] = (unsigned short)(v >> (16 * j));
        }
      }
      __syncthreads();
      if (w == 0 && lane < 16) {
        float s4 = posum[(t - 1) & 1][0][lane] + posum[(t - 1) & 1][1][lane]
                 + posum[(t - 1) & 1][2][lane] + posum[(t - 1) & 1][3][lane];
        partial[((size_t)cb * NB + bm + lane) * NT + (t - 1)] = s4;
      }
    }

#pragma unroll
    for (int xt = 0; xt < 2; ++xt) {
      float v[8];
      *(f32x4*)&v[0] = xr[2 * xt];
      *(f32x4*)&v[4] = xr[2 * xt + 1];
#pragma unroll
      for (int e = 0; e < 8; ++e) ax[xt][e] = (_Float16)v[e];
    }
    acc[0] = (f32x4){0.f, 0.f, 0.f, 0.f};
    acc[1] = (f32x4){0.f, 0.f, 0.f, 0.f};
#pragma unroll
    for (int kt = 0; kt < 16; ++kt) {
      half8 ah = *(const half8*)&hpeer[lm][kt * 32 + lkb];
      acc[0] = __builtin_amdgcn_mfma_f32_16x16x32_f16(ah, wv[kt][0], acc[0], 0, 0, 0);
      acc[1] = __builtin_amdgcn_mfma_f32_16x16x32_f16(ah, wv[kt][1], acc[1], 0, 0, 0);
    }
#pragma unroll
    for (int q = 0; q < 2; ++q) {
      acc[0] = __builtin_amdgcn_mfma_f32_16x16x32_f16(ax[q], wv[16 + q][0], acc[0], 0, 0, 0);
      acc[1] = __builtin_amdgcn_mfma_f32_16x16x32_f16(ax[q], wv[16 + q][1], acc[1], 0, 0, 0);
    }
    if (t + 1 < NT) {
#pragma unroll
      for (int xt = 0; xt < 2; ++xt) {
        xr[2 * xt]     = *(const f32x4*)(xrow + (size_t)(t + 1) * ND + xt * 32);
        xr[2 * xt + 1] = *(const f32x4*)(xrow + (size_t)(t + 1) * ND + xt * 32 + 4);
      }
    }
    __syncthreads();

    float po[4] = {0.f, 0.f, 0.f, 0.f};
#pragma unroll
    for (int nt = 0; nt < 2; ++nt) {
#pragma unroll
      for (int r = 0; r < 4; ++r) {
        float hv  = tanh_fast(acc[nt][r] + bv[nt]);
        const int m = lg * 4 + r;
        const int c = nt * 16 + lm;
        const unsigned short h16 = f16b(hv);
        hpeer[m][n0 + c] = h16;
        tstage[w][c * 16 + m] = h16;
        po[r] += hv * wov[nt];
      }
    }
#pragma unroll
    for (int s = 1; s < 16; s <<= 1)
#pragma unroll
      for (int r = 0; r < 4; ++r) po[r] += __shfl_xor(po[r], s, 64);
    if (lm == 0) {
#pragma unroll
      for (int r = 0; r < 4; ++r) posum[t & 1][w][lg * 4 + r] = po[r];
    }

    {
      const ull tagbits = (ull)(unsigned short)(t + 1) << 48;
      const size_t pubb = (size_t)(t & 1) * STRBUF + mypub;
#pragma unroll
      for (int k = 0; k < 3; ++k) {
        const int g2 = lane + k * 64;
        if (g2 < GRW) {
          ull pk = tagbits;
          const int g3 = 3 * g2;
#pragma unroll
          for (int j = 0; j < 3; ++j) {
            const int p = g3 + j;
            if (p < 512) pk |= (ull)tstage[w][p] << (16 * j);
          }
          __hip_atomic_store(hglob + pubb + g2, pk,
                             __ATOMIC_RELAXED, __HIP_MEMORY_SCOPE_AGENT);
        }
      }
    }
    if (t + 1 < NT) {
      const size_t bufb = (size_t)(t & 1) * STRBUF;
#pragma unroll
      for (int k = 0; k < 9; ++k)
        if (fvalid >> k & 1u)
          fq[k] = __hip_atomic_load(hglob + bufb + foff[k],
                                    __ATOMIC_RELAXED, __HIP_MEMORY_SCOPE_AGENT);
    }
  }

  __syncthreads();
  if (w == 0 && lane < 16) {
    float s4 = posum[(NT - 1) & 1][0][lane] + posum[(NT - 1) & 1][1][lane]
             + posum[(NT - 1) & 1][2][lane] + posum[(NT - 1) & 1][3][lane];
    partial[((size_t)cb * NB + bm + lane) * NT + (NT - 1)] = s4;
  }
}

// ======================= host =======================

extern "C" void kernel_launch(void* const* d_in, const int* in_sizes, int n_in,
                              void* d_out, int out_size, void* d_ws, size_t ws_size,
                              hipStream_t stream) {
  const float* x   = (const float*)d_in[0];
  const float* wih = (const float*)d_in[1];
  const float* whh = (const float*)d_in[2];
  const float* bih = (const float*)d_in[3];
  const float* bhh = (const float*)d_in[4];
  const float* who = (const float*)d_in[5];
  const float* bho = (const float*)d_in[6];
  float* out = (float*)d_out;

  _Float16* wpk = (_Float16*)d_ws;                 // 576 KB
  const size_t wpk_halves = (size_t)18 * 4 * 8 * 64 * 8;   // 294912
  const size_t xpf_halves = (size_t)16 * NT * 8 * 64 * 16; // 67,108,864 (128 MB)
  const size_t need_main = (wpk_halves + xpf_halves) * 2 + 1024;

  prep_kernel<<<144, 256, 0, stream>>>(whh, wih, wpk);

  if (ws_size >= need_main) {
    // -------- main: zero-exchange per-CU recurrence --------
    _Float16* xpf = wpk + wpk_halves;
    xp_kernel<<<512, 512, 0, stream>>>(x, wpk, bih, bhh, xpf);
    rnn_local<<<16, 512, 0, stream>>>(wpk, xpf, who, bho, out);
  } else {
    // -------- fallback: R16 tagged-granule pipeline (proven) --------
    ull* hglob = (ull*)(wpk + wpk_halves);
    float* partial = (float*)(hglob + (size_t)NGTOT);
    init_kernel<<<(NGTOT + 255) / 256, 256, 0, stream>>>(hglob);
    rnn_tag<<<64, 256, 0, stream>>>(x, wpk, bih, bhh, who, hglob, partial);
    combine_kernel<<<512, 256, 0, stream>>>(partial, bho, out);
  }
}